// Round 5
// baseline (135.394 us; speedup 1.0000x reference)
//
#include <hip/hip_runtime.h>

// Shapes (fixed by the reference):
//   frames: (4, 8, 256, 256, 1) f32
//   core:   (4, 256, 256, 200)  f32  -> raw-reshaped to (4, 8, 256, 256, 1, 25)
//   out:    pred_img (4,256,256,1) ++ pred_img_i (4,8,256,256,1), f32
//
// Fused single kernel: block = (b, y, half-row of 128 px) x ALL 8 burst frames.
// n = tid>>5, q = tid&31 (4 px/thread). Computes pred_img_i for all n, then a
// block-level LDS reduction produces pred_img (no second kernel; pred_img_i is
// write-only).
//
// Schedule notes (hard-won):
//  - 25 core float4 loads issued up-front, pinned with sched_barrier(0):
//    without it the scheduler sinks them into the FMA loop (R3: VGPR 60,
//    VALUBusy 3%, 135 us latency-bound).
//  - core loads are NONTEMPORAL: the 210 MB stream must not evict frames
//    from L3 (R3 measured FETCH=207 MB ideal with nt; dropping nt refetches
//    frame halos from HBM).
//  - reduction buffer is DISJOINT from frame smem -> only one tail barrier;
//    pred_i store happens after it so no barrier ever drains the store.
#define H 256
#define W 256

typedef float f4 __attribute__((ext_vector_type(4)));

__global__ __launch_bounds__(256, 3)
void kpn_fused(const float* __restrict__ frames, const float* __restrict__ core,
               float* __restrict__ pred, float* __restrict__ pred_i) {
  // frame staging [n][r][c]: 8 frames x 5 rows x 34 float4 (x = xh*128-4 .. +131)
  __shared__ f4 smem[8 * 5 * 34];   // 21760 B
  __shared__ f4 red[256];           // 4096 B, disjoint -> no reuse barrier

  const int tid = threadIdx.x;
  const int blk = blockIdx.x;          // b*512 + y*2 + xh
  const int xh  = blk & 1;
  const int y   = (blk >> 1) & 255;
  const int b   = blk >> 9;

  const int n = tid >> 5;              // burst frame 0..7
  const int q = tid & 31;              // 4-pixel group within the 128-px half-row

  // ---- issue ALL 25 core loads first (nontemporal); pin them here ----
  const int g = ((b * 8 + n) * 256 + y) * 64 + xh * 32 + q;   // global 4-px group
  const f4* c4 = (const f4*)(core + (size_t)g * 100);
  f4 wv[25];
#pragma unroll
  for (int k = 0; k < 25; ++k) {
    wv[k] = __builtin_nontemporal_load(c4 + k);
  }
  __builtin_amdgcn_sched_barrier(0);   // do NOT sink these loads past staging

  // ---- cooperative frame staging: 8 n x 5 rows x 34 float4 ----
  for (int i = tid; i < 8 * 5 * 34; i += 256) {
    const int nn  = i / 170;           // 170 = 5*34
    const int rem = i - nn * 170;
    const int r   = rem / 34;
    const int c   = rem - r * 34;
    const int yy  = y + r - 2;
    const int x4  = xh * 128 + (c - 1) * 4;   // -4 .. 256 (float4-aligned)
    f4 v = {0.f, 0.f, 0.f, 0.f};
    if ((unsigned)yy < (unsigned)H && (unsigned)x4 <= 252u) {
      v = *(const f4*)(frames + ((size_t)(b * 8 + nn) * H + yy) * W + x4);
    }
    smem[i] = v;
  }
  __syncthreads();

  // ---- compute: 25 taps x 4 pixels ----
  f4 acc = {0.f, 0.f, 0.f, 0.f};
#pragma unroll
  for (int ki = 0; ki < 5; ++ki) {
    const f4* row = &smem[(n * 5 + ki) * 34 + q];   // covers x0-4 .. x0+7
    f4 a0 = row[0], a1 = row[1], a2 = row[2];
    float fr[12] = {a0[0], a0[1], a0[2], a0[3],
                    a1[0], a1[1], a1[2], a1[3],
                    a2[0], a2[1], a2[2], a2[3]};
#pragma unroll
    for (int kj = 0; kj < 5; ++kj) {
#pragma unroll
      for (int p = 0; p < 4; ++p) {
        const int f = p * 25 + ki * 5 + kj;         // compile-time constant
        acc[p] += wv[f >> 2][f & 3] * fr[p + kj + 2];
      }
    }
  }

  // ---- block-level mean over n -> pred (single barrier) ----
  red[tid] = acc;
  __syncthreads();
  if (tid < 32) {
    f4 s = {0.f, 0.f, 0.f, 0.f};
#pragma unroll
    for (int k = 0; k < 8; ++k) {
      s += red[tid + 32 * k];
    }
    s *= 0.125f;
    __builtin_nontemporal_store(
        s, (f4*)(pred + ((size_t)b * 256 + y) * 256 + xh * 128 + tid * 4));
  }

  // ---- pred_img_i store last: nothing after it drains the ack ----
  __builtin_nontemporal_store(acc, (f4*)(pred_i + (size_t)g * 4));
}

extern "C" void kernel_launch(void* const* d_in, const int* in_sizes, int n_in,
                              void* d_out, int out_size, void* d_ws, size_t ws_size,
                              hipStream_t stream) {
  const float* frames = (const float*)d_in[0];
  const float* core   = (const float*)d_in[1];
  float* pred   = (float*)d_out;                     // (4,256,256,1)
  float* pred_i = pred + (size_t)4 * H * W;          // (4,8,256,256,1)

  hipLaunchKernelGGL(kpn_fused, dim3(2048), dim3(256), 0, stream,
                     frames, core, pred, pred_i);
}

// Round 6
// 43.584 us; speedup vs baseline: 3.1065x; 3.1065x over previous
//
#include <hip/hip_runtime.h>

// Shapes (fixed by the reference):
//   frames: (4, 8, 256, 256, 1) f32
//   core:   (4, 256, 256, 200)  f32  -> raw-reshaped to (4, 8, 256, 256, 1, 25)
//   out:    pred_img (4,256,256,1) ++ pred_img_i (4,8,256,256,1), f32
//
// Fused single kernel: block = (b, y, half-row of 128 px) x ALL 8 burst frames.
// n = tid>>5, q = tid&31 (4 px/thread). Computes pred_img_i for all n, then a
// block-level LDS reduction produces pred_img (no second kernel; pred_img_i is
// write-only).
//
// Schedule notes (hard-won, R3-R5):
//  - The 25 core float4 loads MUST be issued up-front and stay in flight
//    (25-deep MLP); when the scheduler sinks them into the FMA loop the
//    kernel is latency-bound (VGPR 60, VALUBusy 3%, 135 us vs 44 us).
//  - __builtin_nontemporal_load on core REINTRODUCES the sink even with
//    sched_barrier(0) (R3, R5). Plain loads only. FETCH stays ~ideal anyway
//    (frame halos hit L2/L3).
//  - Belt+suspenders: keep-alive asm on each loaded vector pins the 25
//    results in registers at that point; sched_barrier(0) fences the region.
#define H 256
#define W 256

typedef float f4 __attribute__((ext_vector_type(4)));

__global__ __launch_bounds__(256, 3)
void kpn_fused(const float* __restrict__ frames, const float* __restrict__ core,
               float* __restrict__ pred, float* __restrict__ pred_i) {
  // frame staging [n][r][c]: 8 frames x 5 rows x 34 float4 (x = xh*128-4 .. +131)
  __shared__ f4 smem[8 * 5 * 34];   // 21760 B
  __shared__ f4 red[256];           // 4096 B, disjoint -> no reuse barrier

  const int tid = threadIdx.x;
  const int blk = blockIdx.x;          // b*512 + y*2 + xh
  const int xh  = blk & 1;
  const int y   = (blk >> 1) & 255;
  const int b   = blk >> 9;

  const int n = tid >> 5;              // burst frame 0..7
  const int q = tid & 31;              // 4-pixel group within the 128-px half-row

  // ---- issue ALL 25 core loads first; pin results live here ----
  const int g = ((b * 8 + n) * 256 + y) * 64 + xh * 32 + q;   // global 4-px group
  const f4* c4 = (const f4*)(core + (size_t)g * 100);
  f4 wv[25];
#pragma unroll
  for (int k = 0; k < 25; ++k) {
    wv[k] = c4[k];
  }
#pragma unroll
  for (int k = 0; k < 25; ++k) {
    asm volatile("" : "+v"(wv[k]));    // materialize in VGPRs NOW (no re-sink)
  }
  __builtin_amdgcn_sched_barrier(0);   // and fence the scheduling region

  // ---- cooperative frame staging: 8 n x 5 rows x 34 float4 ----
  for (int i = tid; i < 8 * 5 * 34; i += 256) {
    const int nn  = i / 170;           // 170 = 5*34
    const int rem = i - nn * 170;
    const int r   = rem / 34;
    const int c   = rem - r * 34;
    const int yy  = y + r - 2;
    const int x4  = xh * 128 + (c - 1) * 4;   // -4 .. 256 (float4-aligned)
    f4 v = {0.f, 0.f, 0.f, 0.f};
    if ((unsigned)yy < (unsigned)H && (unsigned)x4 <= 252u) {
      v = *(const f4*)(frames + ((size_t)(b * 8 + nn) * H + yy) * W + x4);
    }
    smem[i] = v;
  }
  __syncthreads();

  // ---- compute: 25 taps x 4 pixels ----
  f4 acc = {0.f, 0.f, 0.f, 0.f};
#pragma unroll
  for (int ki = 0; ki < 5; ++ki) {
    const f4* row = &smem[(n * 5 + ki) * 34 + q];   // covers x0-4 .. x0+7
    f4 a0 = row[0], a1 = row[1], a2 = row[2];
    float fr[12] = {a0[0], a0[1], a0[2], a0[3],
                    a1[0], a1[1], a1[2], a1[3],
                    a2[0], a2[1], a2[2], a2[3]};
#pragma unroll
    for (int kj = 0; kj < 5; ++kj) {
#pragma unroll
      for (int p = 0; p < 4; ++p) {
        const int f = p * 25 + ki * 5 + kj;         // compile-time constant
        acc[p] += wv[f >> 2][f & 3] * fr[p + kj + 2];
      }
    }
  }

  // ---- block-level mean over n -> pred (single barrier) ----
  red[tid] = acc;
  __syncthreads();
  if (tid < 32) {
    f4 s = {0.f, 0.f, 0.f, 0.f};
#pragma unroll
    for (int k = 0; k < 8; ++k) {
      s += red[tid + 32 * k];
    }
    s *= 0.125f;
    __builtin_nontemporal_store(
        s, (f4*)(pred + ((size_t)b * 256 + y) * 256 + xh * 128 + tid * 4));
  }

  // ---- pred_img_i store last: nothing after it drains the ack ----
  __builtin_nontemporal_store(acc, (f4*)(pred_i + (size_t)g * 4));
}

extern "C" void kernel_launch(void* const* d_in, const int* in_sizes, int n_in,
                              void* d_out, int out_size, void* d_ws, size_t ws_size,
                              hipStream_t stream) {
  const float* frames = (const float*)d_in[0];
  const float* core   = (const float*)d_in[1];
  float* pred   = (float*)d_out;                     // (4,256,256,1)
  float* pred_i = pred + (size_t)4 * H * W;          // (4,8,256,256,1)

  hipLaunchKernelGGL(kpn_fused, dim3(2048), dim3(256), 0, stream,
                     frames, core, pred, pred_i);
}

// Round 7
// 39.211 us; speedup vs baseline: 3.4530x; 1.1115x over previous
//
#include <hip/hip_runtime.h>

// Shapes (fixed by the reference):
//   frames: (4, 8, 256, 256, 1) f32
//   core:   (4, 256, 256, 200)  f32  -> raw-reshaped to (4, 8, 256, 256, 1, 25)
//   out:    pred_img (4,256,256,1) ++ pred_img_i (4,8,256,256,1), f32
//
// Fused single kernel: block = (b, y, half-row of 128 px) x ALL 8 burst frames.
// n = tid>>5, q = tid&31 (4 px/thread). Computes pred_img_i for all n, then a
// block-level LDS reduction produces pred_img (no second kernel; pred_img_i is
// write-only).
//
// Schedule notes (hard-won, R3-R6):
//  - The 25 core float4 loads MUST be issued up-front and stay in flight
//    (25-deep MLP); when the scheduler sinks them into the FMA loop the
//    kernel is latency-bound (VGPR 60, VALUBusy 3%, 135 us vs 44 us).
//  - __builtin_nontemporal_load on core REINTRODUCES the sink even with
//    sched_barrier(0) (R3, R5). Plain loads only.
//  - keep-alive asm on each wv[k] AFTER staging: forces all 100 weight VGPRs
//    live (allocator can't sink loads to satisfy the 128-reg cap) without
//    forcing an early vmcnt(0) drain before staging issues.
//  - __launch_bounds__(256,4): 128-VGPR cap -> 16 waves/CU (R6 had 12);
//    peak live state ~120 regs so it fits without spill.
//  - XCD swizzle (2048 blocks, %8==0 -> bijective): frame-halo re-reads
//    (~44 MB) stay in the local XCD L2 (1.1 MB footprint per chunk).
#define H 256
#define W 256

typedef float f4 __attribute__((ext_vector_type(4)));

__global__ __launch_bounds__(256, 4)
void kpn_fused(const float* __restrict__ frames, const float* __restrict__ core,
               float* __restrict__ pred, float* __restrict__ pred_i) {
  // frame staging [n][r][c]: 8 frames x 5 rows x 34 float4 (x = xh*128-4 .. +131)
  __shared__ f4 smem[8 * 5 * 34];   // 21760 B
  __shared__ f4 red[256];           // 4096 B, disjoint -> no reuse barrier

  const int tid = threadIdx.x;
  const int bid = blockIdx.x;
  // XCD-aware swizzle: consecutive work chunks land on the same XCD's L2.
  const int blk = (bid & 7) * 256 + (bid >> 3);   // bijective for 2048 blocks
  const int xh  = blk & 1;
  const int y   = (blk >> 1) & 255;
  const int b   = blk >> 9;

  const int n = tid >> 5;              // burst frame 0..7
  const int q = tid & 31;              // 4-pixel group within the 128-px half-row

  // ---- issue ALL 25 core loads first; pin the issue point ----
  const int g = ((b * 8 + n) * 256 + y) * 64 + xh * 32 + q;   // global 4-px group
  const f4* c4 = (const f4*)(core + (size_t)g * 100);
  f4 wv[25];
#pragma unroll
  for (int k = 0; k < 25; ++k) {
    wv[k] = c4[k];
  }
  __builtin_amdgcn_sched_barrier(0);   // do NOT sink these loads past staging

  // ---- cooperative frame staging: 8 n x 5 rows x 34 float4 ----
  for (int i = tid; i < 8 * 5 * 34; i += 256) {
    const int nn  = i / 170;           // 170 = 5*34
    const int rem = i - nn * 170;
    const int r   = rem / 34;
    const int c   = rem - r * 34;
    const int yy  = y + r - 2;
    const int x4  = xh * 128 + (c - 1) * 4;   // -4 .. 256 (float4-aligned)
    f4 v = {0.f, 0.f, 0.f, 0.f};
    if ((unsigned)yy < (unsigned)H && (unsigned)x4 <= 252u) {
      v = *(const f4*)(frames + ((size_t)(b * 8 + nn) * H + yy) * W + x4);
    }
    smem[i] = v;
  }
  // Keep all 25 weight vectors live HERE (after staging issued): the register
  // allocator cannot sink the loads, and no early drain blocks staging.
#pragma unroll
  for (int k = 0; k < 25; ++k) {
    asm volatile("" : "+v"(wv[k]));
  }
  __syncthreads();

  // ---- compute: 25 taps x 4 pixels ----
  f4 acc = {0.f, 0.f, 0.f, 0.f};
#pragma unroll
  for (int ki = 0; ki < 5; ++ki) {
    const f4* row = &smem[(n * 5 + ki) * 34 + q];   // covers x0-4 .. x0+7
    f4 a0 = row[0], a1 = row[1], a2 = row[2];
    float fr[12] = {a0[0], a0[1], a0[2], a0[3],
                    a1[0], a1[1], a1[2], a1[3],
                    a2[0], a2[1], a2[2], a2[3]};
#pragma unroll
    for (int kj = 0; kj < 5; ++kj) {
#pragma unroll
      for (int p = 0; p < 4; ++p) {
        const int f = p * 25 + ki * 5 + kj;         // compile-time constant
        acc[p] += wv[f >> 2][f & 3] * fr[p + kj + 2];
      }
    }
  }

  // ---- block-level mean over n -> pred (single barrier) ----
  red[tid] = acc;
  __syncthreads();
  if (tid < 32) {
    f4 s = {0.f, 0.f, 0.f, 0.f};
#pragma unroll
    for (int k = 0; k < 8; ++k) {
      s += red[tid + 32 * k];
    }
    s *= 0.125f;
    __builtin_nontemporal_store(
        s, (f4*)(pred + ((size_t)b * 256 + y) * 256 + xh * 128 + tid * 4));
  }

  // ---- pred_img_i store last: nothing after it drains the ack ----
  __builtin_nontemporal_store(acc, (f4*)(pred_i + (size_t)g * 4));
}

extern "C" void kernel_launch(void* const* d_in, const int* in_sizes, int n_in,
                              void* d_out, int out_size, void* d_ws, size_t ws_size,
                              hipStream_t stream) {
  const float* frames = (const float*)d_in[0];
  const float* core   = (const float*)d_in[1];
  float* pred   = (float*)d_out;                     // (4,256,256,1)
  float* pred_i = pred + (size_t)4 * H * W;          // (4,8,256,256,1)

  hipLaunchKernelGGL(kpn_fused, dim3(2048), dim3(256), 0, stream,
                     frames, core, pred, pred_i);
}

// Round 8
// 37.305 us; speedup vs baseline: 3.6293x; 1.0511x over previous
//
#include <hip/hip_runtime.h>

// Shapes (fixed by the reference):
//   frames: (4, 8, 256, 256, 1) f32
//   core:   (4, 256, 256, 200)  f32  -> raw-reshaped to (4, 8, 256, 256, 1, 25)
//   out:    pred_img (4,256,256,1) ++ pred_img_i (4,8,256,256,1), f32
//
// R8: quad-cooperative core reads. R2..R7 plateaued at 39-44us because each
// core load instruction had 400B lane stride -> 64 distinct cache lines per
// instruction (16B used per access) -> ~13M L2 transactions for core ->
// L2-request-rate-bound (~43us at 128 req/cy chip-wide), not HBM-bound.
// Now 4 lanes (a quad) share one 4-pixel group: lane j loads c4[4m+j], so a
// quad's per-instruction footprint is one contiguous 64B chunk -> ~4x fewer
// L2 transactions. Each lane holds taps at flat floats f=16m+4j+e (24-28 of
// the group's 100 weights), computes partials for all 4 pixels (constexpr
// (p,tap) mapping via switch(j)), then a 2-step quad shfl_xor butterfly.
//
// Carried-over schedule rules (R3-R6): loads issued up-front + pinned with
// sched_barrier(0); NO nontemporal loads (they re-sink); keep-alive asm after
// staging; stores after the last barrier.
#define H 256
#define W 256

typedef float f4 __attribute__((ext_vector_type(4)));

__global__ __launch_bounds__(256, 4)
void kpn_quad(const float* __restrict__ frames, const float* __restrict__ core,
              float* __restrict__ pred, float* __restrict__ pred_i) {
  // frame staging [n][r][c]: 8 frames x 5 rows x 10 float4 (x = xq*32-4 .. +35)
  __shared__ f4 smem[8 * 5 * 10];   // 6400 B
  __shared__ f4 red[64];            // 1 KB, disjoint

  const int tid = threadIdx.x;
  const int bid = blockIdx.x;
  const int blk = (bid & 7) * 1024 + (bid >> 3);   // XCD swizzle (8192%8==0)
  const int xq  = blk & 7;            // 32-px quarter-segment of the row
  const int y   = (blk >> 3) & 255;
  const int b   = blk >> 11;

  const int n = tid >> 5;             // burst frame 0..7
  const int q = (tid >> 2) & 7;       // 4-px group within the 32-px segment
  const int j = tid & 3;              // lane-in-quad

  // ---- quad-cooperative core loads: quad reads contiguous 64B per instr ----
  const int g = ((b * 8 + n) * 256 + y) * 64 + xq * 8 + q;   // global 4-px group
  const f4* c4 = (const f4*)(core + (size_t)g * 100);
  f4 wv[7];
#pragma unroll
  for (int m = 0; m < 6; ++m) {
    wv[m] = c4[4 * m + j];
  }
  wv[6] = c4[24];                     // only j==0 uses it; uniform load is cheap
  __builtin_amdgcn_sched_barrier(0);  // do NOT sink these loads past staging

  // ---- cooperative frame staging: 8 n x 5 rows x 10 float4 ----
  for (int i = tid; i < 400; i += 256) {
    const int nn  = i / 50;
    const int rem = i - nn * 50;
    const int r   = rem / 10;
    const int c   = rem - r * 10;
    const int yy  = y + r - 2;
    const int x4  = xq * 32 + (c - 1) * 4;   // -4 .. 256, float4-aligned
    f4 v = {0.f, 0.f, 0.f, 0.f};
    if ((unsigned)yy < (unsigned)H && (unsigned)x4 <= 252u) {
      v = *(const f4*)(frames + ((size_t)(b * 8 + nn) * H + yy) * W + x4);
    }
    smem[i] = v;
  }
  // keep weight loads live here (allocator can't sink them into the FMAs)
#pragma unroll
  for (int m = 0; m < 7; ++m) {
    asm volatile("" : "+v"(wv[m]));
  }
  __syncthreads();

  // ---- per-lane 12-float window per row (quad-uniform -> LDS broadcast) ----
  f4 w4[5][3];
#pragma unroll
  for (int ki = 0; ki < 5; ++ki) {
    const f4* row = &smem[(n * 5 + ki) * 10 + q];   // floats x0-4 .. x0+7
    w4[ki][0] = row[0]; w4[ki][1] = row[1]; w4[ki][2] = row[2];
  }

  // ---- partial sums: lane j covers flat weights f = 16m+4j+e ----
  f4 acc = {0.f, 0.f, 0.f, 0.f};
#define DO_F(J, M, E)                                                     \
  { constexpr int f  = 16 * (M) + 4 * (J) + (E);                          \
    constexpr int p  = f / 25, kd = f % 25;                               \
    constexpr int ki = kd / 5, kj = kd % 5, wx = p + kj + 2;              \
    acc[p] += wv[M][E] * w4[ki][wx >> 2][wx & 3]; }
#define DO4(J, M) DO_F(J, M, 0) DO_F(J, M, 1) DO_F(J, M, 2) DO_F(J, M, 3)
  switch (j) {
    case 0: DO4(0,0) DO4(0,1) DO4(0,2) DO4(0,3) DO4(0,4) DO4(0,5) DO4(0,6) break;
    case 1: DO4(1,0) DO4(1,1) DO4(1,2) DO4(1,3) DO4(1,4) DO4(1,5) break;
    case 2: DO4(2,0) DO4(2,1) DO4(2,2) DO4(2,3) DO4(2,4) DO4(2,5) break;
    default:DO4(3,0) DO4(3,1) DO4(3,2) DO4(3,3) DO4(3,4) DO4(3,5) break;
  }
#undef DO4
#undef DO_F

  // ---- quad butterfly: every lane gets the full 4-pixel sums ----
#pragma unroll
  for (int c = 0; c < 4; ++c) {
    acc[c] += __shfl_xor(acc[c], 1, 64);
    acc[c] += __shfl_xor(acc[c], 2, 64);
  }

  // ---- block mean over n -> pred (single extra barrier) ----
  if (j == 0) red[tid >> 2] = acc;    // red[n*8+q]
  __syncthreads();
  if (tid < 32) {
    const int qq = tid >> 2, p = tid & 3;
    float s = 0.f;
#pragma unroll
    for (int k = 0; k < 8; ++k) {
      s += red[k * 8 + qq][p];
    }
    s *= 0.125f;
    __builtin_nontemporal_store(
        s, pred + ((size_t)b * 256 + y) * 256 + xq * 32 + tid);
  }

  // ---- pred_img_i: lane j stores pixel j -> fully contiguous wave store ----
  float out = (j == 0) ? acc[0] : (j == 1) ? acc[1] : (j == 2) ? acc[2] : acc[3];
  __builtin_nontemporal_store(out, pred_i + (size_t)g * 4 + j);
}

extern "C" void kernel_launch(void* const* d_in, const int* in_sizes, int n_in,
                              void* d_out, int out_size, void* d_ws, size_t ws_size,
                              hipStream_t stream) {
  const float* frames = (const float*)d_in[0];
  const float* core   = (const float*)d_in[1];
  float* pred   = (float*)d_out;                     // (4,256,256,1)
  float* pred_i = pred + (size_t)4 * H * W;          // (4,8,256,256,1)

  hipLaunchKernelGGL(kpn_quad, dim3(8192), dim3(256), 0, stream,
                     frames, core, pred, pred_i);
}